// Round 21
// baseline (61.123 us; speedup 1.0000x reference)
//
#include <hip/hip_runtime.h>
#include <hip/hip_bf16.h>
#include <cstdint>
#include <cstddef>

// Problem dims (fixed by the reference: B=4, C=256, H=W=64)
#define C_    256
#define C8_   32
#define NPIX  4096
#define BATCH 4
#define OUT_ELEMS (BATCH * C_ * NPIX)   // out [4,256,64,64]; then attention [4096][4096]

typedef short bf16x8 __attribute__((ext_vector_type(8)));   // 8 bf16 in 4 VGPRs
typedef float f32x4  __attribute__((ext_vector_type(4)));
typedef unsigned uint32x2 __attribute__((ext_vector_type(2)));

#define LOG2E 1.44269504088896340736f

// k_attn7 LDS p-staging: per wave [16 rows][520 bf16] (512 data + 8 pad). 130 KB.
#define PROW 520
// k_pre xT tile: [16 n][260 c] f32 (260 = 256 + 4 pad -> write stride 8 banks, 2-way)
#define PADC 260

static __device__ __forceinline__ unsigned short f2bf(float f) {
    union { float f; unsigned u; } v; v.f = f;
    unsigned r = v.u + 0x7fff + ((v.u >> 16) & 1);   // RNE
    return (unsigned short)(r >> 16);
}

// pack two f32 -> two bf16 (TRUNCATE) in one v_perm: low half = p0, high = p1
static __device__ __forceinline__ unsigned pack_bf2(float p0, float p1) {
    union { float f; unsigned u; } a, b; a.f = p0; b.f = p1;
    return __builtin_amdgcn_perm(b.u, a.u, 0x07060302u);
}
static __device__ __forceinline__ float unpk_lo(unsigned u) {
    union { unsigned u; float f; } v; v.u = u << 16; return v.f;
}
static __device__ __forceinline__ float unpk_hi(unsigned u) {
    union { unsigned u; float f; } v; v.u = u & 0xffff0000u; return v.f;
}

static __device__ __forceinline__ f32x4 mfma16(bf16x8 a, bf16x8 b, f32x4 c) {
    return __builtin_amdgcn_mfma_f32_16x16x32_bf16(a, b, c, 0, 0, 0);
}

// ---------------------------------------------------------------------------
// K1 "k_pre" (R21 restructure):
//   [0,1024)    qk projection: block = 16-pixel n-tile, ALL 64 outputs.
//               x staged ONCE (4 MB total, was 32 MB in the 8-o-group split).
//               Thread = (n, o-quad): per 4-c group 1 broadcast ds_read_b128
//               + 4 W f32x4 loads (L1-resident 64 KB) + 16 FMA -> ~9x fewer
//               LDS issues than R20 (which was LDS-issue-bound at ~11 µs).
//               Full-K accumulation per thread: no cross-wave reduce.
//   [1024,2048) out = x copy (overlaps qk; attention no longer carries it).
//   qT,kT: bf16 [B][N][32] (c contiguous). q PRESCALED by log2(e).
//   vB   : bf16 [B][C][N]  (gamma!=0 only, 4 extra Wv chunks)
// ---------------------------------------------------------------------------
__global__ __launch_bounds__(256) void k_pre(
    const float* __restrict__ x,
    const float* __restrict__ Wq, const float* __restrict__ bq,
    const float* __restrict__ Wk, const float* __restrict__ bk,
    const float* __restrict__ Wv, const float* __restrict__ bv,
    const float* __restrict__ gamma,
    float* __restrict__ out,
    unsigned short* __restrict__ qT,
    unsigned short* __restrict__ kT,
    unsigned short* __restrict__ vB)
{
    __shared__ float xsT[16][PADC];   // 16.6 KB x^T tile

    const int bid = blockIdx.x;
    const float gval = gamma[0];
    const int t = threadIdx.x;

    if (bid >= 1024) {                      // ---- copy role (1024 blocks) ----
        const size_t base = (size_t)(bid - 1024) * 1024 + t * 4;   // f32x4 units
        const f32x4* src = (const f32x4*)x;
        f32x4* dst = (f32x4*)out;
#pragma unroll
        for (int k = 0; k < 4; ++k)
            __builtin_nontemporal_store(src[base + k], dst + base + k);
        return;
    }

    // ---- qk projection role ----
    const int b = bid >> 8;                 // 256 blocks per batch
    if (gval == 0.0f && b > 0) return;      // attention only observed at b==0
    const int n0 = (bid & 255) * 16;

    // stage x^T [16 n][256 c]: 16 passes, thread loads x[c = p*16 + t>>4][n0 + (t&15)]
    const int sc = t >> 4;                  // c sub-row 0..15
    const int sn = t & 15;                  // n 0..15
    const float* xb = x + (size_t)b * C_ * NPIX + n0;
    float xv[16];
#pragma unroll
    for (int p = 0; p < 16; ++p)
        xv[p] = xb[(size_t)(p * 16 + sc) * NPIX + sn];
#pragma unroll
    for (int p = 0; p < 16; ++p)
        xsT[sn][p * 16 + sc] = xv[p];
    __syncthreads();

    // compute: thread t -> n = t>>4, o-quad = (t&15)*4 .. +3
    const int n  = t >> 4;
    const int og = t & 15;                  // 0..7 -> q rows, 8..15 -> k rows
    const bool is_q = (og < 8);
    const int o0 = (og & 7) * 4;            // 0,4,..,28 within the 32-row matrix
    const float* Wrow = (is_q ? Wq : Wk) + (size_t)o0 * C_;

    float a0 = 0.f, a1 = 0.f, a2 = 0.f, a3 = 0.f;
#pragma unroll 4
    for (int cq = 0; cq < 64; ++cq) {
        f32x4 xq = *(const f32x4*)&xsT[n][cq * 4];        // broadcast b128
        f32x4 w0 = *(const f32x4*)(Wrow + cq * 4);
        f32x4 w1 = *(const f32x4*)(Wrow + C_ + cq * 4);
        f32x4 w2 = *(const f32x4*)(Wrow + 2 * C_ + cq * 4);
        f32x4 w3 = *(const f32x4*)(Wrow + 3 * C_ + cq * 4);
        a0 = fmaf(w0[0], xq[0], fmaf(w0[1], xq[1], fmaf(w0[2], xq[2], fmaf(w0[3], xq[3], a0))));
        a1 = fmaf(w1[0], xq[0], fmaf(w1[1], xq[1], fmaf(w1[2], xq[2], fmaf(w1[3], xq[3], a1))));
        a2 = fmaf(w2[0], xq[0], fmaf(w2[1], xq[1], fmaf(w2[2], xq[2], fmaf(w2[3], xq[3], a2))));
        a3 = fmaf(w3[0], xq[0], fmaf(w3[1], xq[1], fmaf(w3[2], xq[2], fmaf(w3[3], xq[3], a3))));
    }

    unsigned short h[4];
    if (is_q) {
        h[0] = f2bf((a0 + bq[o0])     * LOG2E);
        h[1] = f2bf((a1 + bq[o0 + 1]) * LOG2E);
        h[2] = f2bf((a2 + bq[o0 + 2]) * LOG2E);
        h[3] = f2bf((a3 + bq[o0 + 3]) * LOG2E);
        *(uint32x2*)(qT + ((size_t)b * NPIX + n0 + n) * C8_ + o0) =
            *(const uint32x2*)h;
    } else {
        h[0] = f2bf(a0 + bk[o0]);
        h[1] = f2bf(a1 + bk[o0 + 1]);
        h[2] = f2bf(a2 + bk[o0 + 2]);
        h[3] = f2bf(a3 + bk[o0 + 3]);
        *(uint32x2*)(kT + ((size_t)b * NPIX + n0 + n) * C8_ + o0) =
            *(const uint32x2*)h;
    }

    // ---- folded v projection (gamma != 0 only): 4 chunks of 64 outputs ----
    if (gval != 0.0f) {
        for (int ch = 0; ch < 4; ++ch) {
            const int vo = ch * 64 + og * 4;          // 4 outputs
            const float* Wvr = Wv + (size_t)vo * C_;
            float v0 = 0.f, v1 = 0.f, v2 = 0.f, v3 = 0.f;
#pragma unroll 4
            for (int cq = 0; cq < 64; ++cq) {
                f32x4 xq = *(const f32x4*)&xsT[n][cq * 4];
                f32x4 w0 = *(const f32x4*)(Wvr + cq * 4);
                f32x4 w1 = *(const f32x4*)(Wvr + C_ + cq * 4);
                f32x4 w2 = *(const f32x4*)(Wvr + 2 * C_ + cq * 4);
                f32x4 w3 = *(const f32x4*)(Wvr + 3 * C_ + cq * 4);
                v0 = fmaf(w0[0], xq[0], fmaf(w0[1], xq[1], fmaf(w0[2], xq[2], fmaf(w0[3], xq[3], v0))));
                v1 = fmaf(w1[0], xq[0], fmaf(w1[1], xq[1], fmaf(w1[2], xq[2], fmaf(w1[3], xq[3], v1))));
                v2 = fmaf(w2[0], xq[0], fmaf(w2[1], xq[1], fmaf(w2[2], xq[2], fmaf(w2[3], xq[3], v2))));
                v3 = fmaf(w3[0], xq[0], fmaf(w3[1], xq[1], fmaf(w3[2], xq[2], fmaf(w3[3], xq[3], v3))));
            }
            const size_t nb = (size_t)b * C_ * NPIX + n0 + n;
            vB[nb + (size_t)(vo)     * NPIX] = f2bf(v0 + bv[vo]);
            vB[nb + (size_t)(vo + 1) * NPIX] = f2bf(v1 + bv[vo + 1]);
            vB[nb + (size_t)(vo + 2) * NPIX] = f2bf(v2 + bv[vo + 2]);
            vB[nb + (size_t)(vo + 3) * NPIX] = f2bf(v3 + bv[vo + 3]);
        }
    }
}

// ---------------------------------------------------------------------------
// K2 "k_attn7": R18's proven attention (20.8 µs incl. copy) with the copy
// role REMOVED (now lives in k_pre, overlapping the projection).
// grid (256,4); gamma==0 && b>0 -> immediate return.
// ---------------------------------------------------------------------------
__global__ __launch_bounds__(512) void k_attn7(
    const float* __restrict__ x,
    const unsigned short* __restrict__ qT,
    const unsigned short* __restrict__ kT,
    const unsigned short* __restrict__ vB,
    const float* __restrict__ gamma,
    float* __restrict__ out,
    float* __restrict__ attn)
{
    const int b = blockIdx.y;
    const float g = gamma[0];
    if (g == 0.0f && b > 0) return;   // copy moved to k_pre

    const int i0   = blockIdx.x * 16;
    const int t    = threadIdx.x;
    const int lane = t & 63;
    const int wavei = __builtin_amdgcn_readfirstlane(t >> 6);  // 0..7
    const int li   = lane & 15;
    const int lg   = lane >> 4;       // 0..3

    __shared__ unsigned short pbuf[8 * 16 * PROW];   // 130 KB p staging (bf16)
    __shared__ float red[8][16];

    const unsigned short* qTb = qT + (size_t)b * NPIX * C8_;
    const unsigned short* kTb = kT + (size_t)b * NPIX * C8_;

    // B fragment (Q, prescaled by log2e): rows i0+li, k-elems lg*8..+7
    bf16x8 qf = *(const bf16x8*)(qTb + (size_t)(i0 + li) * C8_ + lg * 8);

    const int jw = wavei * 512;
    unsigned short* prow = pbuf + (size_t)(wavei * 16 + li) * PROW;

    // one pass: energy -> exp2 -> packed bf16 into LDS + f32 row-sum
    float ssum = 0.f;
#pragma unroll
    for (int s = 0; s < 32; ++s) {
        bf16x8 kf = *(const bf16x8*)(kTb + (size_t)(jw + s * 16 + li) * C8_ + lg * 8);
        f32x4 z = {0.f, 0.f, 0.f, 0.f};
        f32x4 e = mfma16(kf, qf, z);           // e = S * log2e
        float p0 = exp2f(e[0]);
        float p1 = exp2f(e[1]);
        float p2 = exp2f(e[2]);
        float p3 = exp2f(e[3]);
        ssum += (p0 + p1) + (p2 + p3);
        uint32x2 pk;
        pk.x = pack_bf2(p0, p1);
        pk.y = pack_bf2(p2, p3);
        *(uint32x2*)(prow + s * 16 + lg * 4) = pk;   // 8B ds_write_b64
    }

    // row sum: in-wave (across lg) then cross-wave via LDS
    ssum += __shfl_xor(ssum, 16, 64);
    ssum += __shfl_xor(ssum, 32, 64);
    if (lane < 16) red[wavei][lane] = ssum;
    __syncthreads();                   // also makes pbuf visible block-wide
    float l = 0.f;
#pragma unroll
    for (int w = 0; w < 8; ++w) l += red[w][li];
    const float inv = 1.0f / l;        // row i0+li (lanes 0..15 canonical)

    // attention_map write (batch 0): ROW-LINEAR. Wave w owns rows 2w, 2w+1;
    // j segments ascend -> 16KB sequential stream per row.
    if (b == 0) {
#pragma unroll
        for (int rr = 0; rr < 2; ++rr) {
            const int r = wavei * 2 + rr;
            const float inv_r = __shfl(inv, r, 64);
            float* rowp = attn + (size_t)(i0 + r) * NPIX;
#pragma unroll
            for (int seg = 0; seg < 8; ++seg) {
                const unsigned short* rp = pbuf + (size_t)(seg * 16 + r) * PROW;
                uint32x2 u0 = *(const uint32x2*)(rp + lane * 4);        // [0,256)
                uint32x2 u1 = *(const uint32x2*)(rp + 256 + lane * 4);  // [256,512)
                f32x4 v0, v1;
                v0[0] = unpk_lo(u0.x) * inv_r; v0[1] = unpk_hi(u0.x) * inv_r;
                v0[2] = unpk_lo(u0.y) * inv_r; v0[3] = unpk_hi(u0.y) * inv_r;
                v1[0] = unpk_lo(u1.x) * inv_r; v1[1] = unpk_hi(u1.x) * inv_r;
                v1[2] = unpk_lo(u1.y) * inv_r; v1[3] = unpk_hi(u1.y) * inv_r;
                __builtin_nontemporal_store(
                    v0, (f32x4*)(rowp + seg * 512 + lane * 4));
                __builtin_nontemporal_store(
                    v1, (f32x4*)(rowp + seg * 512 + 256 + lane * 4));
            }
        }
    }

    // general path (gamma != 0): PV + out = gamma*attnout + x
    if (g != 0.0f) {
        f32x4 o0 = {0.f, 0.f, 0.f, 0.f};
        f32x4 o1 = {0.f, 0.f, 0.f, 0.f};
        const unsigned short* vb = vB + (size_t)b * C_ * NPIX;
        for (int st = 0; st < 8; ++st) {
            const int jbase = st * 512;
#pragma unroll
            for (int ks = 0; ks < 16; ++ks) {
                bf16x8 af = *(const bf16x8*)(pbuf + (size_t)(st * 16 + li) * PROW +
                                             ks * 32 + lg * 8);      // A[i, j] unnorm
                const unsigned short* vp0 =
                    vb + (size_t)(wavei * 32 + li) * NPIX + jbase + ks * 32 + lg * 8;
                bf16x8 vf0 = *(const bf16x8*)vp0;               // B[j, c-tile0]
                o0 = mfma16(af, vf0, o0);
                bf16x8 vf1 = *(const bf16x8*)(vp0 + (size_t)16 * NPIX);  // c-tile1
                o1 = mfma16(af, vf1, o1);
            }
        }
        // D2[i, c]: lane -> c = c0 + li, i = i0 + lg*4 + r; scale by g*inv[i]
        const float* xbt = x + (size_t)b * C_ * NPIX;
        float* outb = out + (size_t)b * C_ * NPIX;
        f32x4 sc;
#pragma unroll
        for (int r = 0; r < 4; ++r) sc[r] = g * __shfl(inv, lg * 4 + r, 64);
        {
            int c = wavei * 32 + li;
            f32x4 xv = *(const f32x4*)(xbt + (size_t)c * NPIX + i0 + lg * 4);
            f32x4 r0 = o0 * sc + xv;
            *(f32x4*)(outb + (size_t)c * NPIX + i0 + lg * 4) = r0;
            c += 16;
            f32x4 xv1 = *(const f32x4*)(xbt + (size_t)c * NPIX + i0 + lg * 4);
            f32x4 r1 = o1 * sc + xv1;
            *(f32x4*)(outb + (size_t)c * NPIX + i0 + lg * 4) = r1;
        }
    }
}

extern "C" void kernel_launch(void* const* d_in, const int* in_sizes, int n_in,
                              void* d_out, int out_size, void* d_ws, size_t ws_size,
                              hipStream_t stream) {
    (void)in_sizes; (void)n_in; (void)out_size; (void)ws_size;
    const float* x     = (const float*)d_in[0];
    const float* Wq    = (const float*)d_in[1];
    const float* bq    = (const float*)d_in[2];
    const float* Wk    = (const float*)d_in[3];
    const float* bk    = (const float*)d_in[4];
    const float* Wv    = (const float*)d_in[5];
    const float* bv    = (const float*)d_in[6];
    const float* gamma = (const float*)d_in[7];

    float* out  = (float*)d_out;
    float* attn = out + OUT_ELEMS;

    unsigned short* qT = (unsigned short*)d_ws;                       // 1 MB
    unsigned short* kT = qT + (size_t)BATCH * NPIX * C8_;             // 1 MB
    unsigned short* vB = kT + (size_t)BATCH * NPIX * C8_;             // 8 MB (gamma!=0 only)

    k_pre<<<2048, 256, 0, stream>>>(x, Wq, bq, Wk, bk, Wv, bv, gamma,
                                    out, qT, kT, vB);

    dim3 g2(NPIX / 16, BATCH);
    k_attn7<<<g2, 512, 0, stream>>>(x, qT, kT, vB, gamma, out, attn);
}